// Round 1
// baseline (164.655 us; speedup 1.0000x reference)
//
#include <hip/hip_runtime.h>

// CoPE: gated reverse-cumsum positions + interpolated positional logits.
// B=2,H=16,S=2048,D=64,NPOS=64 -> 65536 rows of length 2048.
// One wave (64 lanes) per row; 4 waves per 256-thread block.
//
// Key optimization: suffix sum of sigmoid(gates) grows ~0.5/element going
// backward; once it reaches 63 it is clamped -> pos=63 -> w=0 -> output is
// exactly logits_int[63] for ALL earlier columns. So we scan backward in
// 64-wide chunks, early-exit at carry>=63, and bulk-fill the prefix.
// Reads ~130/2048 attn elements per row instead of all 2048.

#define SLEN 2048
#define DDIM 64
#define NPOS 64

__global__ __launch_bounds__(256) void cope_kernel(
    const float* __restrict__ q,     // [65536, 64]
    const float* __restrict__ attn,  // [65536, 2048]
    const float* __restrict__ emb,   // [64, 64]  (d-major: emb[d*64+n])
    float* __restrict__ out)         // [65536, 2048]
{
    const int lane = threadIdx.x & 63;
    const int wave = threadIdx.x >> 6;
    const int r = blockIdx.x * 4 + wave;   // row id, exactly 65536 rows

    // ---- logits_int[lane] = sum_d q[r][d] * emb[d][lane] ----
    const float qv = q[(size_t)r * DDIM + lane];
    float lv = 0.0f;
    #pragma unroll
    for (int d = 0; d < DDIM; ++d) {
        const float qd = __shfl(qv, d);          // broadcast q[r][d]
        lv = fmaf(qd, emb[d * NPOS + lane], lv); // coalesced, L1-resident
    }
    const float l63 = __shfl(lv, NPOS - 1);

    const float* __restrict__ arow = attn + (size_t)r * SLEN;
    float* __restrict__ orow = out + (size_t)r * SLEN;

    // ---- backward chunked scan with early exit ----
    float carry = 0.0f;   // suffix sum of gates over columns >= jb+64
    int jb = SLEN;
    while (jb > 0) {
        jb -= 64;
        const float x = arow[jb + lane];
        const float g = 1.0f / (1.0f + __expf(-x));   // sigmoid
        // reverse inclusive scan: s[lane] = sum_{k>=lane} g[k]
        float s = g;
        #pragma unroll
        for (int off = 1; off < 64; off <<= 1) {
            const float t = __shfl_down(s, off);
            if (lane + off < 64) s += t;
        }
        const float pos = fminf(carry + s, 63.0f);
        const float pf  = floorf(pos);
        const int  ifl  = (int)pf;
        const int  icl  = (int)ceilf(pos);
        const float w   = pos - pf;
        const float lf  = __shfl(lv, ifl);   // gather from distributed table
        const float lc  = __shfl(lv, icl);
        orow[jb + lane] = lc * w + lf * (1.0f - w);
        carry += __shfl(s, 0);               // lane 0 holds chunk total
        if (carry >= 63.0f) break;           // everything earlier clamps
    }

    // ---- fill [0, jb) with logits_int[63] (pos clamped -> w == 0) ----
    const float4 v4 = make_float4(l63, l63, l63, l63);
    for (int j = lane * 4; j + 3 < jb; j += 256) {
        *reinterpret_cast<float4*>(orow + j) = v4;
    }
}

extern "C" void kernel_launch(void* const* d_in, const int* in_sizes, int n_in,
                              void* d_out, int out_size, void* d_ws, size_t ws_size,
                              hipStream_t stream) {
    const float* q    = (const float*)d_in[0];  // query  [2,16,2048,64]
    const float* attn = (const float*)d_in[1];  // attn_logits [2,16,2048,2048]
    const float* emb  = (const float*)d_in[2];  // pos_emb [1,64,64]
    float* out = (float*)d_out;                 // [2,16,2048,2048]

    const int rows = 2 * 16 * 2048;             // 65536
    dim3 grid(rows / 4), block(256);
    cope_kernel<<<grid, block, 0, stream>>>(q, attn, emb, out);
}